// Round 6
// baseline (352.451 us; speedup 1.0000x reference)
//
#include <hip/hip_runtime.h>

#define B_TOTAL 32768
#define NATOM   512
#define MDIM    64
#define KS      5

// ---------------------------------------------------------------------------
// K0 (fused): blocks [0,512) = perm, blocks [512,1024) = gram.
// perm: dataT[m][b] = z_perm_flat[m*32768+b];  z_perm = transpose(z_e,(0,2,3,1)).
//   For z_e[n,c,h,w]: m = 2n + (h>>4), b = ((h&15)<<11)|(w<<6)|c.
// gram: G = D^T D (one row per block), and zero the loss accumulator.
// ---------------------------------------------------------------------------
__global__ void k_prep(const float* __restrict__ ze, float* __restrict__ dT,
                       const float* __restrict__ D, float* __restrict__ G,
                       float* __restrict__ acc) {
    const int t = threadIdx.x;
    if (blockIdx.x < 512) {
        const int n   = blockIdx.x >> 4;
        const int hw0 = (blockIdx.x & 15) * 64;
        __shared__ float lds[64][65];
#pragma unroll
        for (int r = 0; r < 16; ++r) {
            int id = r * 256 + t;
            int c = id >> 6, i = id & 63;
            lds[c][i] = ze[n * 65536 + c * 1024 + hw0 + i];
        }
        __syncthreads();
#pragma unroll
        for (int r = 0; r < 16; ++r) {
            int id = r * 256 + t;
            int c = id & 63, j = id >> 6;
            int hw = hw0 + j;
            int h = hw >> 5, w = hw & 31;
            int m = (n << 1) | (h >> 4);
            int b = ((h & 15) << 11) | (w << 6) | c;
            dT[m * 32768 + b] = lds[c][j];
        }
    } else {
        const int i = blockIdx.x - 512;
        __shared__ float col[MDIM];
        if (t < MDIM) col[t] = D[t * NATOM + i];
        __syncthreads();
        for (int j = t; j < NATOM; j += 256) {
            float s = 0.f;
#pragma unroll
            for (int m = 0; m < MDIM; ++m) s = fmaf(col[m], D[m * NATOM + j], s);
            G[i * NATOM + j] = s;
        }
        if (i == 0 && t == 0) *acc = 0.f;
    }
}

// ---------------------------------------------------------------------------
// K2: fused h_bar GEMM + per-column OMP.
// Phase 1: block = 4 waves, 32 b; wave computes h_bar for its 8 b.
// Re-stage via LDS so each 8-lane group owns ONE b, 64 atoms/lane
//   (lane p holds atoms n = 32q+4p+s, q=0..15).
// Phase 2: all 8 b of a wave run CONCURRENTLY (one per group).
// LDS: data_s (8.7 KB, phase 1) and stage (32 KB, re-stage) have disjoint
// lifetimes -> union'd in `uni` (34 KB total => 4 blocks/CU by LDS).
// Re-stage rounds are barrier-bracketed (R4 WAR race fix — do not remove).
// Divides: one precise 1/diag per new L row (invD), multiplies elsewhere.
// Private arrays use only compile-time indices (SROA; no scratch).
// ---------------------------------------------------------------------------
__launch_bounds__(256, 3)
__global__ void k_omp(const float* __restrict__ data, const float* __restrict__ D,
                      const float* __restrict__ G, int* __restrict__ idx_out,
                      float* __restrict__ val_out) {
    const int t    = threadIdx.x;
    const int lane = t & 63;
    const int wv   = t >> 6;
    const int b0   = blockIdx.x * 32;

    __shared__ __align__(16) float uni[8192];        // 32 KB union buffer
    __shared__ int   idx_s[KS][32];
    __shared__ float val_s[KS][32];
#define DATA_S(bb, m) uni[(bb) * 68 + (m)]           // 32 x 68 (17x16B rows)

    // stage data tile (64 m x 32 b), coalesced on b
#pragma unroll
    for (int r = 0; r < 8; ++r) {
        int id = r * 256 + t;
        int m = id >> 5, bb = id & 31;
        DATA_S(bb, m) = data[m * B_TOTAL + b0 + bb];
    }
    __syncthreads();

    const float4* __restrict__ D4 = (const float4*)D;
    const float4* __restrict__ G4 = (const float4*)G;

    // ---- phase 1: h_bar accumulators, 8 b x 8 atoms per lane ----
    float4 acc[8][2];
#pragma unroll
    for (int bb = 0; bb < 8; ++bb) {
        acc[bb][0] = make_float4(0.f, 0.f, 0.f, 0.f);
        acc[bb][1] = make_float4(0.f, 0.f, 0.f, 0.f);
    }
    const int bwbase = wv * 8;

#pragma unroll 4
    for (int c = 0; c < 16; ++c) {
        float4 df[4][2];
#pragma unroll
        for (int mm = 0; mm < 4; ++mm) {
            df[mm][0] = D4[(c * 4 + mm) * 128 + lane];
            df[mm][1] = D4[(c * 4 + mm) * 128 + 64 + lane];
        }
#pragma unroll
        for (int bb = 0; bb < 8; ++bb) {
            const float4 dv = *(const float4*)&DATA_S(bwbase + bb, c * 4);
            const float dm[4] = {dv.x, dv.y, dv.z, dv.w};
#pragma unroll
            for (int mm = 0; mm < 4; ++mm) {
                acc[bb][0].x = fmaf(df[mm][0].x, dm[mm], acc[bb][0].x);
                acc[bb][0].y = fmaf(df[mm][0].y, dm[mm], acc[bb][0].y);
                acc[bb][0].z = fmaf(df[mm][0].z, dm[mm], acc[bb][0].z);
                acc[bb][0].w = fmaf(df[mm][0].w, dm[mm], acc[bb][0].w);
                acc[bb][1].x = fmaf(df[mm][1].x, dm[mm], acc[bb][1].x);
                acc[bb][1].y = fmaf(df[mm][1].y, dm[mm], acc[bb][1].y);
                acc[bb][1].z = fmaf(df[mm][1].z, dm[mm], acc[bb][1].z);
                acc[bb][1].w = fmaf(df[mm][1].w, dm[mm], acc[bb][1].w);
            }
        }
    }

    // ---- re-stage: acc(8b x 8 atoms) -> hb(64 atoms of group's b) ----
    // stage region = uni[wv*2048 ..]; stage[q2*512+n] = h_bar[n] of b#(r*4+q2).
    const int g = lane >> 3;       // group = b within wave's 8
    const int p = lane & 7;        // lane within group
    float hb[64];
#pragma unroll
    for (int r = 0; r < 2; ++r) {
        __syncthreads();           // round r-1 reads complete before overwrite
#pragma unroll
        for (int q2 = 0; q2 < 4; ++q2) {
            int bb = r * 4 + q2;
            *(float4*)&uni[wv * 2048 + q2 * 512 + 4 * lane]       = acc[bb][0];
            *(float4*)&uni[wv * 2048 + q2 * 512 + 256 + 4 * lane] = acc[bb][1];
        }
        __syncthreads();           // writes committed before reads
        if ((g >> 2) == r) {
#pragma unroll
            for (int q = 0; q < 16; ++q) {
                const float4 v =
                    *(const float4*)&uni[wv * 2048 + (g & 3) * 512 + 32 * q + 4 * p];
                hb[4 * q + 0] = v.x;
                hb[4 * q + 1] = v.y;
                hb[4 * q + 2] = v.z;
                hb[4 * q + 3] = v.w;
            }
        }
    }

    // ---- phase 2: OMP, 8 concurrent b (one per 8-lane group) ----
    float key[64];
#pragma unroll
    for (int e = 0; e < 64; ++e) key[e] = fabsf(hb[e]);

    unsigned msk0 = 0u, msk1 = 0u;
    int   I[KS];
    float xs[KS];
    float gsel[KS];
    float Lm[15];                   // packed lower-tri
    float invD[KS];                 // 1 / diag(L)

#pragma unroll
    for (int k = 0; k < KS; ++k) {
        // --- argmax: 8 independent chunk scans (depth 8) + tournament (3) ---
        // Tie semantics == linear first-max: every pairing compares a
        // lower-index range vs a higher one and keeps lower on ties.
        float cv[8]; int ce[8]; float ch[8];
#pragma unroll
        for (int c0 = 0; c0 < 8; ++c0) {
            float bv0 = key[8 * c0]; int be0 = 8 * c0; float bh0 = hb[8 * c0];
#pragma unroll
            for (int e = 1; e < 8; ++e) {
                int ee = 8 * c0 + e;
                bool gt = key[ee] > bv0;
                bv0 = gt ? key[ee] : bv0;
                be0 = gt ? ee      : be0;
                bh0 = gt ? hb[ee]  : bh0;
            }
            cv[c0] = bv0; ce[c0] = be0; ch[c0] = bh0;
        }
#pragma unroll
        for (int s = 1; s < 8; s <<= 1) {
#pragma unroll
            for (int c0 = 0; c0 < 8; c0 += 2 * s) {
                bool gt = cv[c0 + s] > cv[c0];
                cv[c0] = gt ? cv[c0 + s] : cv[c0];
                ce[c0] = gt ? ce[c0 + s] : ce[c0];
                ch[c0] = gt ? ch[c0 + s] : ch[c0];
            }
        }
        float bv = cv[0]; float bhb = ch[0];
        int   bn = 32 * (ce[0] >> 2) + 4 * p + (ce[0] & 3);

        // --- 3-step reduce across the 8-lane group ---
#pragma unroll
        for (int off = 1; off < 8; off <<= 1) {
            float ov  = __shfl_xor(bv, off);
            int   on  = __shfl_xor(bn, off);
            float ohb = __shfl_xor(bhb, off);
            bool take = (ov > bv) || (ov == bv && on < bn);
            bv = take ? ov : bv; bn = take ? on : bn; bhb = take ? ohb : bhb;
        }
        const int nsel = bn;                // group-uniform
        I[k]    = nsel;
        gsel[k] = bhb;                      // = h_bar[nsel] (original), exact

        // mask the selected atom for future scans
        {
            int own  = (nsel >> 2) & 7;
            int esel = ((nsel >> 5) << 2) | (nsel & 3);
            if (p == own) {
                if (esel < 32) msk0 |= 1u << esel;
                else           msk1 |= 1u << (esel - 32);
            }
        }

        // --- Cholesky update of L ---
        if (k > 0) {
            float gk[KS - 1], w[KS - 1];
#pragma unroll
            for (int ti = 0; ti < KS - 1; ++ti)
                if (ti < k) gk[ti] = G[I[ti] * NATOM + nsel];
#pragma unroll
            for (int r = 0; r < KS - 1; ++r) {
                if (r < k) {
                    float s = gk[r];
#pragma unroll
                    for (int cc = 0; cc < KS - 1; ++cc)
                        if (cc < r) s -= Lm[r * (r + 1) / 2 + cc] * w[cc];
                    w[r] = s * invD[r];
                }
            }
            float s2 = 0.f;
#pragma unroll
            for (int r = 0; r < KS - 1; ++r) if (r < k) s2 += w[r] * w[r];
            float wc = sqrtf(fmaxf(0.f, 1.f - s2));
#pragma unroll
            for (int cc = 0; cc < KS - 1; ++cc)
                if (cc < k) Lm[k * (k + 1) / 2 + cc] = w[cc];
            Lm[k * (k + 1) / 2 + k] = wc;
            invD[k] = 1.0f / wc;            // the one precise divide per k
        } else {
            Lm[0] = 1.f;
            invD[0] = 1.f;
        }

        // --- solve L y = gsel ; L^T x = y (replicated within group) ---
        float y[KS];
#pragma unroll
        for (int r = 0; r <= k; ++r) {
            float s = gsel[r];
#pragma unroll
            for (int cc = 0; cc < r; ++cc) s -= Lm[r * (r + 1) / 2 + cc] * y[cc];
            y[r] = s * invD[r];
        }
#pragma unroll
        for (int r = k; r >= 0; --r) {
            float s = y[r];
#pragma unroll
            for (int cc = r + 1; cc <= k; ++cc) s -= Lm[cc * (cc + 1) / 2 + r] * xs[cc];
            xs[r] = s * invD[r];
        }

        // --- fused beta + key update (no beta[] array; ascending-ti fma) ---
        if (k < KS - 1) {
#pragma unroll
            for (int q = 0; q < 16; ++q) {
                float bx = 0.f, by = 0.f, bz = 0.f, bw = 0.f;
#pragma unroll
                for (int ti = 0; ti < KS - 1; ++ti) {
                    if (ti <= k) {
                        const float4 gc = G4[I[ti] * 128 + 8 * q + p];
                        bx = fmaf(xs[ti], gc.x, bx);
                        by = fmaf(xs[ti], gc.y, by);
                        bz = fmaf(xs[ti], gc.z, bz);
                        bw = fmaf(xs[ti], gc.w, bw);
                    }
                }
                {
                    float d0 = hb[4 * q + 0] - bx;
                    float d1 = hb[4 * q + 1] - by;
                    float d2 = hb[4 * q + 2] - bz;
                    float d3 = hb[4 * q + 3] - bw;
                    const int e0 = 4 * q;
                    bool m0 = (e0 + 0 < 32) ? ((msk0 >> (e0 + 0)) & 1u) : ((msk1 >> (e0 - 32)) & 1u);
                    bool m1 = (e0 + 1 < 32) ? ((msk0 >> (e0 + 1)) & 1u) : ((msk1 >> (e0 + 1 - 32)) & 1u);
                    bool m2 = (e0 + 2 < 32) ? ((msk0 >> (e0 + 2)) & 1u) : ((msk1 >> (e0 + 2 - 32)) & 1u);
                    bool m3 = (e0 + 3 < 32) ? ((msk0 >> (e0 + 3)) & 1u) : ((msk1 >> (e0 + 3 - 32)) & 1u);
                    key[e0 + 0] = m0 ? -1.f : fabsf(d0);
                    key[e0 + 1] = m1 ? -1.f : fabsf(d1);
                    key[e0 + 2] = m2 ? -1.f : fabsf(d2);
                    key[e0 + 3] = m3 ? -1.f : fabsf(d3);
                }
            }
        }
    }

    if (p == 0) {
#pragma unroll
        for (int k = 0; k < KS; ++k) {
            idx_s[k][wv * 8 + g] = I[k];
            val_s[k][wv * 8 + g] = xs[k];
        }
    }
    __syncthreads();
    if (t < KS * 32) {
        int k = t >> 5, bb = t & 31;
        idx_out[k * B_TOTAL + b0 + bb] = idx_s[k][bb];
        val_out[k * B_TOTAL + b0 + bb] = val_s[k][bb];
    }
#undef DATA_S
}

// ---------------------------------------------------------------------------
// K3a: expand sparse (idx,val) into dense 512 x 32768 coefficients.
// 4 b per thread; int4/float4 loads, float4 stores (1 KB per wave-store).
// ---------------------------------------------------------------------------
__global__ void k_coeff(const int* __restrict__ idx, const float* __restrict__ val,
                        float* __restrict__ coeff) {
    const int tile = blockIdx.x >> 3;            // 32 tiles of 1024 b
    const int jc   = blockIdx.x & 7;             // 8 j-chunks of 64
    const int b4   = tile * 1024 + threadIdx.x * 4;
    int4   I[KS]; float4 V[KS];
#pragma unroll
    for (int k = 0; k < KS; ++k) {
        I[k] = *(const int4*)  &idx[k * B_TOTAL + b4];
        V[k] = *(const float4*)&val[k * B_TOTAL + b4];
    }
    const int j0 = jc * 64;
#pragma unroll 4
    for (int j = j0; j < j0 + 64; ++j) {
        float4 w = make_float4(0.f, 0.f, 0.f, 0.f);
#pragma unroll
        for (int k = 0; k < KS; ++k) {
            w.x = (I[k].x == j) ? V[k].x : w.x;
            w.y = (I[k].y == j) ? V[k].y : w.y;
            w.z = (I[k].z == j) ? V[k].z : w.z;
            w.w = (I[k].w == j) ? V[k].w : w.w;
        }
        *(float4*)&coeff[j * B_TOTAL + b4] = w;
    }
}

// ---------------------------------------------------------------------------
// K3b: z_out + loss. b-major compute (coalesced idx/val/dataT reads,
// D row L1-hot), LDS tile transpose for coalesced z_e-layout writes.
// ---------------------------------------------------------------------------
__global__ void k_recon(const float* __restrict__ dataT, const float* __restrict__ D,
                        const int* __restrict__ idx, const float* __restrict__ val,
                        float* __restrict__ zout, float* __restrict__ acc) {
    const int n   = blockIdx.x >> 4;
    const int hw0 = (blockIdx.x & 15) * 64;
    const int t   = threadIdx.x;
    __shared__ float lds[64][65];
    float sq = 0.f;
#pragma unroll
    for (int r = 0; r < 16; ++r) {
        int id = r * 256 + t;
        int c = id & 63, j = id >> 6;
        int f = n * 65536 + (hw0 + j) * 64 + c;
        int b = f & 32767;
        int m = f >> 15;
        float zdl = 0.f;
#pragma unroll
        for (int k = 0; k < KS; ++k) {
            int   a = idx[k * B_TOTAL + b];
            float v = val[k * B_TOTAL + b];
            zdl = fmaf(v, D[m * NATOM + a], zdl);
        }
        float zp   = dataT[f];
        float diff = zdl - zp;
        lds[c][j] = zp + diff;
        sq = fmaf(diff, diff, sq);
    }
    __syncthreads();
#pragma unroll
    for (int r = 0; r < 16; ++r) {
        int id = r * 256 + t;
        int cc = id >> 6, i = id & 63;
        zout[n * 65536 + cc * 1024 + hw0 + i] = lds[cc][i];
    }
#pragma unroll
    for (int off = 32; off > 0; off >>= 1) sq += __shfl_xor(sq, off);
    __shared__ float red[4];
    if ((t & 63) == 0) red[t >> 6] = sq;
    __syncthreads();
    if (t == 0) atomicAdd(acc, red[0] + red[1] + red[2] + red[3]);
}

// ---------------------------------------------------------------------------
// K4: finalize loss = 1.25 * mean(diff^2)
// ---------------------------------------------------------------------------
__global__ void k_loss(const float* __restrict__ acc, float* __restrict__ out_loss) {
    if (threadIdx.x == 0 && blockIdx.x == 0)
        *out_loss = 1.25f * (*acc / 2097152.f);
}

// ---------------------------------------------------------------------------
extern "C" void kernel_launch(void* const* d_in, const int* in_sizes, int n_in,
                              void* d_out, int out_size, void* d_ws, size_t ws_size,
                              hipStream_t stream) {
    const float* ze = (const float*)d_in[0];
    const float* D  = (const float*)d_in[1];

    float* G     = (float*)d_ws;
    int*   idxp  = (int*)  ((char*)d_ws + (size_t)262144 * 4);
    float* valp  = (float*)((char*)d_ws + (size_t)(262144 + 163840) * 4);
    float* accp  = (float*)((char*)d_ws + (size_t)(262144 + 2 * 163840) * 4);
    float* dataT = (float*)((char*)d_ws + (size_t)(262144 + 2 * 163840 + 64) * 4);

    float* zout  = (float*)d_out;
    float* lossp = zout + 2097152;
    float* coeff = zout + 2097153;

    k_prep <<<1024, 256, 0, stream>>>(ze, dataT, D, G, accp);
    k_omp  <<<1024, 256, 0, stream>>>(dataT, D, G, idxp, valp);
    k_coeff<<<256, 256, 0, stream>>>(idxp, valp, coeff);
    k_recon<<<512, 256, 0, stream>>>(dataT, D, idxp, valp, zout, accp);
    k_loss <<<1, 64, 0, stream>>>(accp, lossp);
}

// Round 7
// 222.515 us; speedup vs baseline: 1.5839x; 1.5839x over previous
//
#include <hip/hip_runtime.h>

#define B_TOTAL 32768
#define NATOM   512
#define MDIM    64
#define KS      5

// ---------------------------------------------------------------------------
// K0 (fused): blocks [0,512) = perm, blocks [512,1024) = gram.
// perm: dataT[m][b] = z_perm_flat[m*32768+b];  z_perm = transpose(z_e,(0,2,3,1)).
//   For z_e[n,c,h,w]: m = 2n + (h>>4), b = ((h&15)<<11)|(w<<6)|c.
// gram: G = D^T D (one row per block), and zero the loss accumulator.
// ---------------------------------------------------------------------------
__global__ void k_prep(const float* __restrict__ ze, float* __restrict__ dT,
                       const float* __restrict__ D, float* __restrict__ G,
                       float* __restrict__ acc) {
    const int t = threadIdx.x;
    if (blockIdx.x < 512) {
        const int n   = blockIdx.x >> 4;
        const int hw0 = (blockIdx.x & 15) * 64;
        __shared__ float lds[64][65];
#pragma unroll
        for (int r = 0; r < 16; ++r) {
            int id = r * 256 + t;
            int c = id >> 6, i = id & 63;
            lds[c][i] = ze[n * 65536 + c * 1024 + hw0 + i];
        }
        __syncthreads();
#pragma unroll
        for (int r = 0; r < 16; ++r) {
            int id = r * 256 + t;
            int c = id & 63, j = id >> 6;
            int hw = hw0 + j;
            int h = hw >> 5, w = hw & 31;
            int m = (n << 1) | (h >> 4);
            int b = ((h & 15) << 11) | (w << 6) | c;
            dT[m * 32768 + b] = lds[c][j];
        }
    } else {
        const int i = blockIdx.x - 512;
        __shared__ float col[MDIM];
        if (t < MDIM) col[t] = D[t * NATOM + i];
        __syncthreads();
        for (int j = t; j < NATOM; j += 256) {
            float s = 0.f;
#pragma unroll
            for (int m = 0; m < MDIM; ++m) s = fmaf(col[m], D[m * NATOM + j], s);
            G[i * NATOM + j] = s;
        }
        if (i == 0 && t == 0) *acc = 0.f;
    }
}

// ---------------------------------------------------------------------------
// K2: fused h_bar GEMM + per-column OMP.
// Phase 1: block = 4 waves, 32 b; wave computes h_bar for its 8 b.
// Re-stage via LDS so each 8-lane group owns ONE b, 64 atoms/lane
//   (lane p holds atoms n = 32q+4p+s, q=0..15).
// Phase 2: all 8 b of a wave run CONCURRENTLY (one per group).
// LDS: data_s (8.7 KB) and stage (32 KB) lifetimes disjoint -> union (34 KB).
// Re-stage rounds are barrier-bracketed (R4 WAR race fix — do not remove).
// Divides: one precise 1/diag per new L row (invD), multiplies elsewhere.
// Private arrays use only compile-time indices (SROA; no scratch).
// *** __launch_bounds__ MUST stay (256,2): (256,3) forces the allocator to
// *** spill hb/key wholesale (VGPR=84, ~290 MB scratch traffic) — measured
// *** twice (R3, R6). (256,2) allocates ~128-170 and runs clean (R5).
// ---------------------------------------------------------------------------
__launch_bounds__(256, 2)
__global__ void k_omp(const float* __restrict__ data, const float* __restrict__ D,
                      const float* __restrict__ G, int* __restrict__ idx_out,
                      float* __restrict__ val_out) {
    const int t    = threadIdx.x;
    const int lane = t & 63;
    const int wv   = t >> 6;
    const int b0   = blockIdx.x * 32;

    __shared__ __align__(16) float uni[8192];        // 32 KB union buffer
    __shared__ int   idx_s[KS][32];
    __shared__ float val_s[KS][32];
#define DATA_S(bb, m) uni[(bb) * 68 + (m)]           // 32 x 68

    // stage data tile (64 m x 32 b), coalesced on b
#pragma unroll
    for (int r = 0; r < 8; ++r) {
        int id = r * 256 + t;
        int m = id >> 5, bb = id & 31;
        DATA_S(bb, m) = data[m * B_TOTAL + b0 + bb];
    }
    __syncthreads();

    const float4* __restrict__ D4 = (const float4*)D;
    const float4* __restrict__ G4 = (const float4*)G;

    // ---- phase 1: h_bar accumulators, 8 b x 8 atoms per lane ----
    float4 acc[8][2];
#pragma unroll
    for (int bb = 0; bb < 8; ++bb) {
        acc[bb][0] = make_float4(0.f, 0.f, 0.f, 0.f);
        acc[bb][1] = make_float4(0.f, 0.f, 0.f, 0.f);
    }
    const int bwbase = wv * 8;

#pragma unroll 4
    for (int c = 0; c < 16; ++c) {
        float4 df[4][2];
#pragma unroll
        for (int mm = 0; mm < 4; ++mm) {
            df[mm][0] = D4[(c * 4 + mm) * 128 + lane];
            df[mm][1] = D4[(c * 4 + mm) * 128 + 64 + lane];
        }
#pragma unroll
        for (int bb = 0; bb < 8; ++bb) {
            const float4 dv = *(const float4*)&DATA_S(bwbase + bb, c * 4);
            const float dm[4] = {dv.x, dv.y, dv.z, dv.w};
#pragma unroll
            for (int mm = 0; mm < 4; ++mm) {
                acc[bb][0].x = fmaf(df[mm][0].x, dm[mm], acc[bb][0].x);
                acc[bb][0].y = fmaf(df[mm][0].y, dm[mm], acc[bb][0].y);
                acc[bb][0].z = fmaf(df[mm][0].z, dm[mm], acc[bb][0].z);
                acc[bb][0].w = fmaf(df[mm][0].w, dm[mm], acc[bb][0].w);
                acc[bb][1].x = fmaf(df[mm][1].x, dm[mm], acc[bb][1].x);
                acc[bb][1].y = fmaf(df[mm][1].y, dm[mm], acc[bb][1].y);
                acc[bb][1].z = fmaf(df[mm][1].z, dm[mm], acc[bb][1].z);
                acc[bb][1].w = fmaf(df[mm][1].w, dm[mm], acc[bb][1].w);
            }
        }
    }

    // ---- re-stage: acc(8b x 8 atoms) -> hb(64 atoms of group's b) ----
    const int g = lane >> 3;       // group = b within wave's 8
    const int p = lane & 7;        // lane within group
    float hb[64];
#pragma unroll
    for (int r = 0; r < 2; ++r) {
        __syncthreads();           // round r-1 reads complete before overwrite
#pragma unroll
        for (int q2 = 0; q2 < 4; ++q2) {
            int bb = r * 4 + q2;
            *(float4*)&uni[wv * 2048 + q2 * 512 + 4 * lane]       = acc[bb][0];
            *(float4*)&uni[wv * 2048 + q2 * 512 + 256 + 4 * lane] = acc[bb][1];
        }
        __syncthreads();           // writes committed before reads
        if ((g >> 2) == r) {
#pragma unroll
            for (int q = 0; q < 16; ++q) {
                const float4 v =
                    *(const float4*)&uni[wv * 2048 + (g & 3) * 512 + 32 * q + 4 * p];
                hb[4 * q + 0] = v.x;
                hb[4 * q + 1] = v.y;
                hb[4 * q + 2] = v.z;
                hb[4 * q + 3] = v.w;
            }
        }
    }

    // ---- phase 2: OMP, 8 concurrent b (one per 8-lane group) ----
    float key[64];
#pragma unroll
    for (int e = 0; e < 64; ++e) key[e] = fabsf(hb[e]);

    unsigned msk0 = 0u, msk1 = 0u;
    int   I[KS];
    float xs[KS];
    float gsel[KS];
    float Lm[15];                   // packed lower-tri
    float invD[KS];                 // 1 / diag(L)

#pragma unroll
    for (int k = 0; k < KS; ++k) {
        // --- argmax: 8 chunk scans (depth 8) + tournament (depth 3) ---
        // Tie semantics == linear first-max: every pairing compares a
        // lower-index range vs a higher one and keeps lower on ties.
        float cv[8]; int ce[8]; float ch[8];
#pragma unroll
        for (int c0 = 0; c0 < 8; ++c0) {
            float bv0 = key[8 * c0]; int be0 = 8 * c0; float bh0 = hb[8 * c0];
#pragma unroll
            for (int e = 1; e < 8; ++e) {
                int ee = 8 * c0 + e;
                bool gt = key[ee] > bv0;
                bv0 = gt ? key[ee] : bv0;
                be0 = gt ? ee      : be0;
                bh0 = gt ? hb[ee]  : bh0;
            }
            cv[c0] = bv0; ce[c0] = be0; ch[c0] = bh0;
        }
#pragma unroll
        for (int s = 1; s < 8; s <<= 1) {
#pragma unroll
            for (int c0 = 0; c0 < 8; c0 += 2 * s) {
                bool gt = cv[c0 + s] > cv[c0];
                cv[c0] = gt ? cv[c0 + s] : cv[c0];
                ce[c0] = gt ? ce[c0 + s] : ce[c0];
                ch[c0] = gt ? ch[c0 + s] : ch[c0];
            }
        }
        float bv = cv[0]; float bhb = ch[0];
        int   bn = 32 * (ce[0] >> 2) + 4 * p + (ce[0] & 3);

        // --- 3-step reduce across the 8-lane group ---
#pragma unroll
        for (int off = 1; off < 8; off <<= 1) {
            float ov  = __shfl_xor(bv, off);
            int   on  = __shfl_xor(bn, off);
            float ohb = __shfl_xor(bhb, off);
            bool take = (ov > bv) || (ov == bv && on < bn);
            bv = take ? ov : bv; bn = take ? on : bn; bhb = take ? ohb : bhb;
        }
        const int nsel = bn;                // group-uniform
        I[k]    = nsel;
        gsel[k] = bhb;                      // = h_bar[nsel] (original), exact

        // mask the selected atom for future scans
        {
            int own  = (nsel >> 2) & 7;
            int esel = ((nsel >> 5) << 2) | (nsel & 3);
            if (p == own) {
                if (esel < 32) msk0 |= 1u << esel;
                else           msk1 |= 1u << (esel - 32);
            }
        }

        // --- Cholesky update of L ---
        if (k > 0) {
            float gk[KS - 1], w[KS - 1];
#pragma unroll
            for (int ti = 0; ti < KS - 1; ++ti)
                if (ti < k) gk[ti] = G[I[ti] * NATOM + nsel];
#pragma unroll
            for (int r = 0; r < KS - 1; ++r) {
                if (r < k) {
                    float s = gk[r];
#pragma unroll
                    for (int cc = 0; cc < KS - 1; ++cc)
                        if (cc < r) s -= Lm[r * (r + 1) / 2 + cc] * w[cc];
                    w[r] = s * invD[r];
                }
            }
            float s2 = 0.f;
#pragma unroll
            for (int r = 0; r < KS - 1; ++r) if (r < k) s2 += w[r] * w[r];
            float wc = sqrtf(fmaxf(0.f, 1.f - s2));
#pragma unroll
            for (int cc = 0; cc < KS - 1; ++cc)
                if (cc < k) Lm[k * (k + 1) / 2 + cc] = w[cc];
            Lm[k * (k + 1) / 2 + k] = wc;
            invD[k] = 1.0f / wc;            // one precise divide per k
        } else {
            Lm[0] = 1.f;
            invD[0] = 1.f;
        }

        // --- solve L y = gsel ; L^T x = y (replicated within group) ---
        float y[KS];
#pragma unroll
        for (int r = 0; r <= k; ++r) {
            float s = gsel[r];
#pragma unroll
            for (int cc = 0; cc < r; ++cc) s -= Lm[r * (r + 1) / 2 + cc] * y[cc];
            y[r] = s * invD[r];
        }
#pragma unroll
        for (int r = k; r >= 0; --r) {
            float s = y[r];
#pragma unroll
            for (int cc = r + 1; cc <= k; ++cc) s -= Lm[cc * (cc + 1) / 2 + r] * xs[cc];
            xs[r] = s * invD[r];
        }

        // --- fused beta + key update (no beta[] array; ascending-ti fma) ---
        if (k < KS - 1) {
#pragma unroll
            for (int q = 0; q < 16; ++q) {
                float bx = 0.f, by = 0.f, bz = 0.f, bw = 0.f;
#pragma unroll
                for (int ti = 0; ti < KS - 1; ++ti) {
                    if (ti <= k) {
                        const float4 gc = G4[I[ti] * 128 + 8 * q + p];
                        bx = fmaf(xs[ti], gc.x, bx);
                        by = fmaf(xs[ti], gc.y, by);
                        bz = fmaf(xs[ti], gc.z, bz);
                        bw = fmaf(xs[ti], gc.w, bw);
                    }
                }
                {
                    float d0 = hb[4 * q + 0] - bx;
                    float d1 = hb[4 * q + 1] - by;
                    float d2 = hb[4 * q + 2] - bz;
                    float d3 = hb[4 * q + 3] - bw;
                    const int e0 = 4 * q;
                    bool m0 = (e0 + 0 < 32) ? ((msk0 >> (e0 + 0)) & 1u) : ((msk1 >> (e0 - 32)) & 1u);
                    bool m1 = (e0 + 1 < 32) ? ((msk0 >> (e0 + 1)) & 1u) : ((msk1 >> (e0 + 1 - 32)) & 1u);
                    bool m2 = (e0 + 2 < 32) ? ((msk0 >> (e0 + 2)) & 1u) : ((msk1 >> (e0 + 2 - 32)) & 1u);
                    bool m3 = (e0 + 3 < 32) ? ((msk0 >> (e0 + 3)) & 1u) : ((msk1 >> (e0 + 3 - 32)) & 1u);
                    key[e0 + 0] = m0 ? -1.f : fabsf(d0);
                    key[e0 + 1] = m1 ? -1.f : fabsf(d1);
                    key[e0 + 2] = m2 ? -1.f : fabsf(d2);
                    key[e0 + 3] = m3 ? -1.f : fabsf(d3);
                }
            }
        }
    }

    if (p == 0) {
#pragma unroll
        for (int k = 0; k < KS; ++k) {
            idx_s[k][wv * 8 + g] = I[k];
            val_s[k][wv * 8 + g] = xs[k];
        }
    }
    __syncthreads();
    if (t < KS * 32) {
        int k = t >> 5, bb = t & 31;
        idx_out[k * B_TOTAL + b0 + bb] = idx_s[k][bb];
        val_out[k * B_TOTAL + b0 + bb] = val_s[k][bb];
    }
#undef DATA_S
}

// ---------------------------------------------------------------------------
// K3a: expand sparse (idx,val) into dense 512 x 32768 coefficients.
// 4 b per thread; int4/float4 loads, float4 stores.
// ---------------------------------------------------------------------------
__global__ void k_coeff(const int* __restrict__ idx, const float* __restrict__ val,
                        float* __restrict__ coeff) {
    const int tile = blockIdx.x >> 3;            // 32 tiles of 1024 b
    const int jc   = blockIdx.x & 7;             // 8 j-chunks of 64
    const int b4   = tile * 1024 + threadIdx.x * 4;
    int4   I[KS]; float4 V[KS];
#pragma unroll
    for (int k = 0; k < KS; ++k) {
        I[k] = *(const int4*)  &idx[k * B_TOTAL + b4];
        V[k] = *(const float4*)&val[k * B_TOTAL + b4];
    }
    const int j0 = jc * 64;
#pragma unroll 4
    for (int j = j0; j < j0 + 64; ++j) {
        float4 w = make_float4(0.f, 0.f, 0.f, 0.f);
#pragma unroll
        for (int k = 0; k < KS; ++k) {
            w.x = (I[k].x == j) ? V[k].x : w.x;
            w.y = (I[k].y == j) ? V[k].y : w.y;
            w.z = (I[k].z == j) ? V[k].z : w.z;
            w.w = (I[k].w == j) ? V[k].w : w.w;
        }
        *(float4*)&coeff[j * B_TOTAL + b4] = w;
    }
}

// ---------------------------------------------------------------------------
// K3b: z_out + loss. b-major compute (coalesced idx/val/dataT reads,
// D row L1-hot), LDS tile transpose for coalesced z_e-layout writes.
// ---------------------------------------------------------------------------
__global__ void k_recon(const float* __restrict__ dataT, const float* __restrict__ D,
                        const int* __restrict__ idx, const float* __restrict__ val,
                        float* __restrict__ zout, float* __restrict__ acc) {
    const int n   = blockIdx.x >> 4;
    const int hw0 = (blockIdx.x & 15) * 64;
    const int t   = threadIdx.x;
    __shared__ float lds[64][65];
    float sq = 0.f;
#pragma unroll
    for (int r = 0; r < 16; ++r) {
        int id = r * 256 + t;
        int c = id & 63, j = id >> 6;
        int f = n * 65536 + (hw0 + j) * 64 + c;
        int b = f & 32767;
        int m = f >> 15;
        float zdl = 0.f;
#pragma unroll
        for (int k = 0; k < KS; ++k) {
            int   a = idx[k * B_TOTAL + b];
            float v = val[k * B_TOTAL + b];
            zdl = fmaf(v, D[m * NATOM + a], zdl);
        }
        float zp   = dataT[f];
        float diff = zdl - zp;
        lds[c][j] = zp + diff;
        sq = fmaf(diff, diff, sq);
    }
    __syncthreads();
#pragma unroll
    for (int r = 0; r < 16; ++r) {
        int id = r * 256 + t;
        int cc = id >> 6, i = id & 63;
        zout[n * 65536 + cc * 1024 + hw0 + i] = lds[cc][i];
    }
#pragma unroll
    for (int off = 32; off > 0; off >>= 1) sq += __shfl_xor(sq, off);
    __shared__ float red[4];
    if ((t & 63) == 0) red[t >> 6] = sq;
    __syncthreads();
    if (t == 0) atomicAdd(acc, red[0] + red[1] + red[2] + red[3]);
}

// ---------------------------------------------------------------------------
// K4: finalize loss = 1.25 * mean(diff^2)
// ---------------------------------------------------------------------------
__global__ void k_loss(const float* __restrict__ acc, float* __restrict__ out_loss) {
    if (threadIdx.x == 0 && blockIdx.x == 0)
        *out_loss = 1.25f * (*acc / 2097152.f);
}

// ---------------------------------------------------------------------------
extern "C" void kernel_launch(void* const* d_in, const int* in_sizes, int n_in,
                              void* d_out, int out_size, void* d_ws, size_t ws_size,
                              hipStream_t stream) {
    const float* ze = (const float*)d_in[0];
    const float* D  = (const float*)d_in[1];

    float* G     = (float*)d_ws;
    int*   idxp  = (int*)  ((char*)d_ws + (size_t)262144 * 4);
    float* valp  = (float*)((char*)d_ws + (size_t)(262144 + 163840) * 4);
    float* accp  = (float*)((char*)d_ws + (size_t)(262144 + 2 * 163840) * 4);
    float* dataT = (float*)((char*)d_ws + (size_t)(262144 + 2 * 163840 + 64) * 4);

    float* zout  = (float*)d_out;
    float* lossp = zout + 2097152;
    float* coeff = zout + 2097153;

    k_prep <<<1024, 256, 0, stream>>>(ze, dataT, D, G, accp);
    k_omp  <<<1024, 256, 0, stream>>>(dataT, D, G, idxp, valp);
    k_coeff<<<256, 256, 0, stream>>>(idxp, valp, coeff);
    k_recon<<<512, 256, 0, stream>>>(dataT, D, idxp, valp, zout, accp);
    k_loss <<<1, 64, 0, stream>>>(accp, lossp);
}

// Round 8
// 220.574 us; speedup vs baseline: 1.5979x; 1.0088x over previous
//
#include <hip/hip_runtime.h>

#define B_TOTAL 32768
#define NATOM   512
#define MDIM    64
#define KS      5

// ---------------------------------------------------------------------------
// K0 (fused): blocks [0,512) = perm, blocks [512,1024) = gram.
// perm: dataT[m][b] = z_perm_flat[m*32768+b];  z_perm = transpose(z_e,(0,2,3,1)).
//   For z_e[n,c,h,w]: m = 2n + (h>>4), b = ((h&15)<<11)|(w<<6)|c.
// gram: G = D^T D (one row per block); zero loss accumulator + completion cnt.
// ---------------------------------------------------------------------------
__global__ void k_prep(const float* __restrict__ ze, float* __restrict__ dT,
                       const float* __restrict__ D, float* __restrict__ G,
                       float* __restrict__ acc, unsigned* __restrict__ cnt) {
    const int t = threadIdx.x;
    if (blockIdx.x < 512) {
        const int n   = blockIdx.x >> 4;
        const int hw0 = (blockIdx.x & 15) * 64;
        __shared__ float lds[64][65];
#pragma unroll
        for (int r = 0; r < 16; ++r) {
            int id = r * 256 + t;
            int c = id >> 6, i = id & 63;
            lds[c][i] = ze[n * 65536 + c * 1024 + hw0 + i];
        }
        __syncthreads();
#pragma unroll
        for (int r = 0; r < 16; ++r) {
            int id = r * 256 + t;
            int c = id & 63, j = id >> 6;
            int hw = hw0 + j;
            int h = hw >> 5, w = hw & 31;
            int m = (n << 1) | (h >> 4);
            int b = ((h & 15) << 11) | (w << 6) | c;
            dT[m * 32768 + b] = lds[c][j];
        }
    } else {
        const int i = blockIdx.x - 512;
        __shared__ float col[MDIM];
        if (t < MDIM) col[t] = D[t * NATOM + i];
        __syncthreads();
        for (int j = t; j < NATOM; j += 256) {
            float s = 0.f;
#pragma unroll
            for (int m = 0; m < MDIM; ++m) s = fmaf(col[m], D[m * NATOM + j], s);
            G[i * NATOM + j] = s;
        }
        if (i == 0 && t == 0) { *acc = 0.f; *cnt = 0u; }
    }
}

// ---------------------------------------------------------------------------
// K2: fused h_bar GEMM + per-column OMP.
// Phase 1: block = 4 waves, 32 b; wave computes h_bar for its 8 b.
// Re-stage via LDS so each 8-lane group owns ONE b, 64 atoms/lane.
// Phase 2: all 8 b of a wave run CONCURRENTLY (one per group).
// Re-stage rounds are barrier-bracketed (R4 WAR race fix — do not remove).
// *** REGISTER-PRESSURE CLIFF (measured R3/R5/R6/R7): the allocator targets
// *** 128 VGPR and SPILLS any excess at phase-2 peak (hb[64]+key[64]+~15
// *** scalars just fits). Tournament argmax (+24 live regs) => 42 MB scratch
// *** (R7, 103us). launch_bounds(256,3) => wholesale spill (R3/R6, 290 MB).
// *** Keep (256,2); keep argmax as a running linear scan (3 live regs);
// *** any phase-2 change must be pressure-neutral.
// ---------------------------------------------------------------------------
__launch_bounds__(256, 2)
__global__ void k_omp(const float* __restrict__ data, const float* __restrict__ D,
                      const float* __restrict__ G, int* __restrict__ idx_out,
                      float* __restrict__ val_out) {
    const int t    = threadIdx.x;
    const int lane = t & 63;
    const int wv   = t >> 6;
    const int b0   = blockIdx.x * 32;

    __shared__ __align__(16) float uni[8192];        // 32 KB union buffer
    __shared__ int   idx_s[KS][32];
    __shared__ float val_s[KS][32];
#define DATA_S(bb, m) uni[(bb) * 68 + (m)]           // 32 x 68

    // stage data tile (64 m x 32 b), coalesced on b
#pragma unroll
    for (int r = 0; r < 8; ++r) {
        int id = r * 256 + t;
        int m = id >> 5, bb = id & 31;
        DATA_S(bb, m) = data[m * B_TOTAL + b0 + bb];
    }
    __syncthreads();

    const float4* __restrict__ D4 = (const float4*)D;
    const float4* __restrict__ G4 = (const float4*)G;

    // ---- phase 1: h_bar accumulators, 8 b x 8 atoms per lane ----
    float4 acc[8][2];
#pragma unroll
    for (int bb = 0; bb < 8; ++bb) {
        acc[bb][0] = make_float4(0.f, 0.f, 0.f, 0.f);
        acc[bb][1] = make_float4(0.f, 0.f, 0.f, 0.f);
    }
    const int bwbase = wv * 8;

#pragma unroll 4
    for (int c = 0; c < 16; ++c) {
        float4 df[4][2];
#pragma unroll
        for (int mm = 0; mm < 4; ++mm) {
            df[mm][0] = D4[(c * 4 + mm) * 128 + lane];
            df[mm][1] = D4[(c * 4 + mm) * 128 + 64 + lane];
        }
#pragma unroll
        for (int bb = 0; bb < 8; ++bb) {
            const float4 dv = *(const float4*)&DATA_S(bwbase + bb, c * 4);
            const float dm[4] = {dv.x, dv.y, dv.z, dv.w};
#pragma unroll
            for (int mm = 0; mm < 4; ++mm) {
                acc[bb][0].x = fmaf(df[mm][0].x, dm[mm], acc[bb][0].x);
                acc[bb][0].y = fmaf(df[mm][0].y, dm[mm], acc[bb][0].y);
                acc[bb][0].z = fmaf(df[mm][0].z, dm[mm], acc[bb][0].z);
                acc[bb][0].w = fmaf(df[mm][0].w, dm[mm], acc[bb][0].w);
                acc[bb][1].x = fmaf(df[mm][1].x, dm[mm], acc[bb][1].x);
                acc[bb][1].y = fmaf(df[mm][1].y, dm[mm], acc[bb][1].y);
                acc[bb][1].z = fmaf(df[mm][1].z, dm[mm], acc[bb][1].z);
                acc[bb][1].w = fmaf(df[mm][1].w, dm[mm], acc[bb][1].w);
            }
        }
    }

    // ---- re-stage: acc(8b x 8 atoms) -> hb(64 atoms of group's b) ----
    const int g = lane >> 3;       // group = b within wave's 8
    const int p = lane & 7;        // lane within group
    float hb[64];
#pragma unroll
    for (int r = 0; r < 2; ++r) {
        __syncthreads();           // round r-1 reads complete before overwrite
#pragma unroll
        for (int q2 = 0; q2 < 4; ++q2) {
            int bb = r * 4 + q2;
            *(float4*)&uni[wv * 2048 + q2 * 512 + 4 * lane]       = acc[bb][0];
            *(float4*)&uni[wv * 2048 + q2 * 512 + 256 + 4 * lane] = acc[bb][1];
        }
        __syncthreads();           // writes committed before reads
        if ((g >> 2) == r) {
#pragma unroll
            for (int q = 0; q < 16; ++q) {
                const float4 v =
                    *(const float4*)&uni[wv * 2048 + (g & 3) * 512 + 32 * q + 4 * p];
                hb[4 * q + 0] = v.x;
                hb[4 * q + 1] = v.y;
                hb[4 * q + 2] = v.z;
                hb[4 * q + 3] = v.w;
            }
        }
    }

    // ---- phase 2: OMP, 8 concurrent b (one per 8-lane group) ----
    float key[64];
#pragma unroll
    for (int e = 0; e < 64; ++e) key[e] = fabsf(hb[e]);

    unsigned msk0 = 0u, msk1 = 0u;
    int   I[KS];
    float xs[KS];
    float gsel[KS];
    float Lm[15];                   // packed lower-tri
    float invD[KS];                 // 1 / diag(L)

#pragma unroll
    for (int k = 0; k < KS; ++k) {
        // --- local argmax: running linear scan (3 live regs; do not widen) ---
        float bv = key[0]; int be = 0; float bhb = hb[0];
#pragma unroll
        for (int e = 1; e < 64; ++e) {
            bool gt = key[e] > bv;          // strict > keeps lowest e (n asc.)
            bv  = gt ? key[e] : bv;
            be  = gt ? e      : be;
            bhb = gt ? hb[e]  : bhb;
        }
        int bn = 32 * (be >> 2) + 4 * p + (be & 3);

        // --- 3-step reduce across the 8-lane group ---
#pragma unroll
        for (int off = 1; off < 8; off <<= 1) {
            float ov  = __shfl_xor(bv, off);
            int   on  = __shfl_xor(bn, off);
            float ohb = __shfl_xor(bhb, off);
            bool take = (ov > bv) || (ov == bv && on < bn);
            bv = take ? ov : bv; bn = take ? on : bn; bhb = take ? ohb : bhb;
        }
        const int nsel = bn;                // group-uniform
        I[k]    = nsel;
        gsel[k] = bhb;                      // = h_bar[nsel] (original), exact

        // mask the selected atom for future scans
        {
            int own  = (nsel >> 2) & 7;
            int esel = ((nsel >> 5) << 2) | (nsel & 3);
            if (p == own) {
                if (esel < 32) msk0 |= 1u << esel;
                else           msk1 |= 1u << (esel - 32);
            }
        }

        // --- Cholesky update of L ---
        if (k > 0) {
            float gk[KS - 1], w[KS - 1];
#pragma unroll
            for (int ti = 0; ti < KS - 1; ++ti)
                if (ti < k) gk[ti] = G[I[ti] * NATOM + nsel];
#pragma unroll
            for (int r = 0; r < KS - 1; ++r) {
                if (r < k) {
                    float s = gk[r];
#pragma unroll
                    for (int cc = 0; cc < KS - 1; ++cc)
                        if (cc < r) s -= Lm[r * (r + 1) / 2 + cc] * w[cc];
                    w[r] = s * invD[r];
                }
            }
            float s2 = 0.f;
#pragma unroll
            for (int r = 0; r < KS - 1; ++r) if (r < k) s2 += w[r] * w[r];
            float wc = sqrtf(fmaxf(0.f, 1.f - s2));
#pragma unroll
            for (int cc = 0; cc < KS - 1; ++cc)
                if (cc < k) Lm[k * (k + 1) / 2 + cc] = w[cc];
            Lm[k * (k + 1) / 2 + k] = wc;
            invD[k] = 1.0f / wc;            // one precise divide per k
        } else {
            Lm[0] = 1.f;
            invD[0] = 1.f;
        }

        // --- solve L y = gsel ; L^T x = y (replicated within group) ---
        float y[KS];
#pragma unroll
        for (int r = 0; r <= k; ++r) {
            float s = gsel[r];
#pragma unroll
            for (int cc = 0; cc < r; ++cc) s -= Lm[r * (r + 1) / 2 + cc] * y[cc];
            y[r] = s * invD[r];
        }
#pragma unroll
        for (int r = k; r >= 0; --r) {
            float s = y[r];
#pragma unroll
            for (int cc = r + 1; cc <= k; ++cc) s -= Lm[cc * (cc + 1) / 2 + r] * xs[cc];
            xs[r] = s * invD[r];
        }

        // --- fused beta + key update (no beta[] array; ascending-ti fma) ---
        if (k < KS - 1) {
#pragma unroll
            for (int q = 0; q < 16; ++q) {
                float bx = 0.f, by = 0.f, bz = 0.f, bw = 0.f;
#pragma unroll
                for (int ti = 0; ti < KS - 1; ++ti) {
                    if (ti <= k) {
                        const float4 gc = G4[I[ti] * 128 + 8 * q + p];
                        bx = fmaf(xs[ti], gc.x, bx);
                        by = fmaf(xs[ti], gc.y, by);
                        bz = fmaf(xs[ti], gc.z, bz);
                        bw = fmaf(xs[ti], gc.w, bw);
                    }
                }
                {
                    float d0 = hb[4 * q + 0] - bx;
                    float d1 = hb[4 * q + 1] - by;
                    float d2 = hb[4 * q + 2] - bz;
                    float d3 = hb[4 * q + 3] - bw;
                    const int e0 = 4 * q;
                    bool m0 = (e0 + 0 < 32) ? ((msk0 >> (e0 + 0)) & 1u) : ((msk1 >> (e0 - 32)) & 1u);
                    bool m1 = (e0 + 1 < 32) ? ((msk0 >> (e0 + 1)) & 1u) : ((msk1 >> (e0 + 1 - 32)) & 1u);
                    bool m2 = (e0 + 2 < 32) ? ((msk0 >> (e0 + 2)) & 1u) : ((msk1 >> (e0 + 2 - 32)) & 1u);
                    bool m3 = (e0 + 3 < 32) ? ((msk0 >> (e0 + 3)) & 1u) : ((msk1 >> (e0 + 3 - 32)) & 1u);
                    key[e0 + 0] = m0 ? -1.f : fabsf(d0);
                    key[e0 + 1] = m1 ? -1.f : fabsf(d1);
                    key[e0 + 2] = m2 ? -1.f : fabsf(d2);
                    key[e0 + 3] = m3 ? -1.f : fabsf(d3);
                }
            }
        }
    }

    if (p == 0) {
#pragma unroll
        for (int k = 0; k < KS; ++k) {
            idx_s[k][wv * 8 + g] = I[k];
            val_s[k][wv * 8 + g] = xs[k];
        }
    }
    __syncthreads();
    if (t < KS * 32) {
        int k = t >> 5, bb = t & 31;
        idx_out[k * B_TOTAL + b0 + bb] = idx_s[k][bb];
        val_out[k * B_TOTAL + b0 + bb] = val_s[k][bb];
    }
#undef DATA_S
}

// ---------------------------------------------------------------------------
// K3 (fused tail): blocks [0,512) = recon+loss, [512,768) = coeff expand.
// recon: b-major compute, LDS tile transpose for coalesced z_e-layout writes;
//        per-block loss partial -> device atomicAdd; LAST recon block (via
//        device-scope counter, after __threadfence) finalizes the loss.
// coeff: 4 b per thread; int4/float4 loads, float4 stores.
// ---------------------------------------------------------------------------
__global__ void k_post(const float* __restrict__ dataT, const float* __restrict__ D,
                       const int* __restrict__ idx, const float* __restrict__ val,
                       float* __restrict__ zout, float* __restrict__ coeff,
                       float* __restrict__ acc, unsigned* __restrict__ cnt,
                       float* __restrict__ lossp) {
    const int t = threadIdx.x;
    if (blockIdx.x < 512) {
        const int n   = blockIdx.x >> 4;
        const int hw0 = (blockIdx.x & 15) * 64;
        __shared__ float lds[64][65];
        float sq = 0.f;
#pragma unroll
        for (int r = 0; r < 16; ++r) {
            int id = r * 256 + t;
            int c = id & 63, j = id >> 6;
            int f = n * 65536 + (hw0 + j) * 64 + c;
            int b = f & 32767;
            int m = f >> 15;
            float zdl = 0.f;
#pragma unroll
            for (int k = 0; k < KS; ++k) {
                int   a = idx[k * B_TOTAL + b];
                float v = val[k * B_TOTAL + b];
                zdl = fmaf(v, D[m * NATOM + a], zdl);
            }
            float zp   = dataT[f];
            float diff = zdl - zp;
            lds[c][j] = zp + diff;
            sq = fmaf(diff, diff, sq);
        }
        __syncthreads();
#pragma unroll
        for (int r = 0; r < 16; ++r) {
            int id = r * 256 + t;
            int cc = id >> 6, i = id & 63;
            zout[n * 65536 + cc * 1024 + hw0 + i] = lds[cc][i];
        }
#pragma unroll
        for (int off = 32; off > 0; off >>= 1) sq += __shfl_xor(sq, off);
        __shared__ float red[4];
        if ((t & 63) == 0) red[t >> 6] = sq;
        __syncthreads();
        if (t == 0) {
            atomicAdd(acc, red[0] + red[1] + red[2] + red[3]);
            __threadfence();
            unsigned old = atomicAdd(cnt, 1u);
            if (old == 511u) {
                float total = atomicAdd(acc, 0.0f);   // coherent device read
                *lossp = 1.25f * (total / 2097152.f);
            }
        }
    } else {
        const int bb   = blockIdx.x - 512;
        const int tile = bb >> 3;                 // 32 tiles of 1024 b
        const int jc   = bb & 7;                  // 8 j-chunks of 64
        const int b4   = tile * 1024 + t * 4;
        int4   I[KS]; float4 V[KS];
#pragma unroll
        for (int k = 0; k < KS; ++k) {
            I[k] = *(const int4*)  &idx[k * B_TOTAL + b4];
            V[k] = *(const float4*)&val[k * B_TOTAL + b4];
        }
        const int j0 = jc * 64;
#pragma unroll 4
        for (int j = j0; j < j0 + 64; ++j) {
            float4 w = make_float4(0.f, 0.f, 0.f, 0.f);
#pragma unroll
            for (int k = 0; k < KS; ++k) {
                w.x = (I[k].x == j) ? V[k].x : w.x;
                w.y = (I[k].y == j) ? V[k].y : w.y;
                w.z = (I[k].z == j) ? V[k].z : w.z;
                w.w = (I[k].w == j) ? V[k].w : w.w;
            }
            *(float4*)&coeff[j * B_TOTAL + b4] = w;
        }
    }
}

// ---------------------------------------------------------------------------
extern "C" void kernel_launch(void* const* d_in, const int* in_sizes, int n_in,
                              void* d_out, int out_size, void* d_ws, size_t ws_size,
                              hipStream_t stream) {
    const float* ze = (const float*)d_in[0];
    const float* D  = (const float*)d_in[1];

    float*    G     = (float*)d_ws;
    int*      idxp  = (int*)     ((char*)d_ws + (size_t)262144 * 4);
    float*    valp  = (float*)   ((char*)d_ws + (size_t)(262144 + 163840) * 4);
    float*    accp  = (float*)   ((char*)d_ws + (size_t)(262144 + 2 * 163840) * 4);
    unsigned* cntp  = (unsigned*)((char*)d_ws + (size_t)(262144 + 2 * 163840 + 1) * 4);
    float*    dataT = (float*)   ((char*)d_ws + (size_t)(262144 + 2 * 163840 + 64) * 4);

    float* zout  = (float*)d_out;
    float* lossp = zout + 2097152;
    float* coeff = zout + 2097153;

    k_prep<<<1024, 256, 0, stream>>>(ze, dataT, D, G, accp, cntp);
    k_omp <<<1024, 256, 0, stream>>>(dataT, D, G, idxp, valp);
    k_post<<<768, 256, 0, stream>>>(dataT, D, idxp, valp, zout, coeff,
                                    accp, cntp, lossp);
}

// Round 9
// 200.306 us; speedup vs baseline: 1.7596x; 1.1012x over previous
//
#include <hip/hip_runtime.h>

#define B_TOTAL 32768
#define NATOM   512
#define MDIM    64
#define KS      5

// ---------------------------------------------------------------------------
// K0 (fused): blocks [0,512) = perm, blocks [512,1024) = gram.
// perm: dataT[m][b] = z_perm_flat[m*32768+b];  z_perm = transpose(z_e,(0,2,3,1)).
//   For z_e[n,c,h,w]: m = 2n + (h>>4), b = ((h&15)<<11)|(w<<6)|c.
// gram: G = D^T D (one row per block); zero loss accumulator.
// ---------------------------------------------------------------------------
__global__ void k_prep(const float* __restrict__ ze, float* __restrict__ dT,
                       const float* __restrict__ D, float* __restrict__ G,
                       float* __restrict__ acc) {
    const int t = threadIdx.x;
    if (blockIdx.x < 512) {
        const int n   = blockIdx.x >> 4;
        const int hw0 = (blockIdx.x & 15) * 64;
        __shared__ float lds[64][65];
#pragma unroll
        for (int r = 0; r < 16; ++r) {
            int id = r * 256 + t;
            int c = id >> 6, i = id & 63;
            lds[c][i] = ze[n * 65536 + c * 1024 + hw0 + i];
        }
        __syncthreads();
#pragma unroll
        for (int r = 0; r < 16; ++r) {
            int id = r * 256 + t;
            int c = id & 63, j = id >> 6;
            int hw = hw0 + j;
            int h = hw >> 5, w = hw & 31;
            int m = (n << 1) | (h >> 4);
            int b = ((h & 15) << 11) | (w << 6) | c;
            dT[m * 32768 + b] = lds[c][j];
        }
    } else {
        const int i = blockIdx.x - 512;
        __shared__ float col[MDIM];
        if (t < MDIM) col[t] = D[t * NATOM + i];
        __syncthreads();
        for (int j = t; j < NATOM; j += 256) {
            float s = 0.f;
#pragma unroll
            for (int m = 0; m < MDIM; ++m) s = fmaf(col[m], D[m * NATOM + j], s);
            G[i * NATOM + j] = s;
        }
        if (i == 0 && t == 0) *acc = 0.f;
    }
}

// ---------------------------------------------------------------------------
// K2: fused h_bar GEMM + per-column OMP.  (FROZEN from R8 — known-good.)
// Phase 1: block = 4 waves, 32 b; wave computes h_bar for its 8 b.
// Re-stage via LDS so each 8-lane group owns ONE b, 64 atoms/lane.
// Phase 2: all 8 b of a wave run CONCURRENTLY (one per group).
// Re-stage rounds are barrier-bracketed (R4 WAR race fix — do not remove).
// *** REGISTER-PRESSURE CLIFF (measured R3/R5/R6/R7): allocator targets 128
// *** VGPR and SPILLS any excess at phase-2 peak (hb[64]+key[64]+~15 scalars
// *** just fits). Tournament argmax (+24 live) => 42 MB scratch (R7).
// *** launch_bounds(256,3) => wholesale spill (R3/R6, ~290 MB).
// *** Keep (256,2); keep linear-scan argmax; pressure-neutral changes only.
// ---------------------------------------------------------------------------
__launch_bounds__(256, 2)
__global__ void k_omp(const float* __restrict__ data, const float* __restrict__ D,
                      const float* __restrict__ G, int* __restrict__ idx_out,
                      float* __restrict__ val_out) {
    const int t    = threadIdx.x;
    const int lane = t & 63;
    const int wv   = t >> 6;
    const int b0   = blockIdx.x * 32;

    __shared__ __align__(16) float uni[8192];        // 32 KB union buffer
    __shared__ int   idx_s[KS][32];
    __shared__ float val_s[KS][32];
#define DATA_S(bb, m) uni[(bb) * 68 + (m)]           // 32 x 68

    // stage data tile (64 m x 32 b), coalesced on b
#pragma unroll
    for (int r = 0; r < 8; ++r) {
        int id = r * 256 + t;
        int m = id >> 5, bb = id & 31;
        DATA_S(bb, m) = data[m * B_TOTAL + b0 + bb];
    }
    __syncthreads();

    const float4* __restrict__ D4 = (const float4*)D;
    const float4* __restrict__ G4 = (const float4*)G;

    // ---- phase 1: h_bar accumulators, 8 b x 8 atoms per lane ----
    float4 acc[8][2];
#pragma unroll
    for (int bb = 0; bb < 8; ++bb) {
        acc[bb][0] = make_float4(0.f, 0.f, 0.f, 0.f);
        acc[bb][1] = make_float4(0.f, 0.f, 0.f, 0.f);
    }
    const int bwbase = wv * 8;

#pragma unroll 4
    for (int c = 0; c < 16; ++c) {
        float4 df[4][2];
#pragma unroll
        for (int mm = 0; mm < 4; ++mm) {
            df[mm][0] = D4[(c * 4 + mm) * 128 + lane];
            df[mm][1] = D4[(c * 4 + mm) * 128 + 64 + lane];
        }
#pragma unroll
        for (int bb = 0; bb < 8; ++bb) {
            const float4 dv = *(const float4*)&DATA_S(bwbase + bb, c * 4);
            const float dm[4] = {dv.x, dv.y, dv.z, dv.w};
#pragma unroll
            for (int mm = 0; mm < 4; ++mm) {
                acc[bb][0].x = fmaf(df[mm][0].x, dm[mm], acc[bb][0].x);
                acc[bb][0].y = fmaf(df[mm][0].y, dm[mm], acc[bb][0].y);
                acc[bb][0].z = fmaf(df[mm][0].z, dm[mm], acc[bb][0].z);
                acc[bb][0].w = fmaf(df[mm][0].w, dm[mm], acc[bb][0].w);
                acc[bb][1].x = fmaf(df[mm][1].x, dm[mm], acc[bb][1].x);
                acc[bb][1].y = fmaf(df[mm][1].y, dm[mm], acc[bb][1].y);
                acc[bb][1].z = fmaf(df[mm][1].z, dm[mm], acc[bb][1].z);
                acc[bb][1].w = fmaf(df[mm][1].w, dm[mm], acc[bb][1].w);
            }
        }
    }

    // ---- re-stage: acc(8b x 8 atoms) -> hb(64 atoms of group's b) ----
    const int g = lane >> 3;       // group = b within wave's 8
    const int p = lane & 7;        // lane within group
    float hb[64];
#pragma unroll
    for (int r = 0; r < 2; ++r) {
        __syncthreads();           // round r-1 reads complete before overwrite
#pragma unroll
        for (int q2 = 0; q2 < 4; ++q2) {
            int bb = r * 4 + q2;
            *(float4*)&uni[wv * 2048 + q2 * 512 + 4 * lane]       = acc[bb][0];
            *(float4*)&uni[wv * 2048 + q2 * 512 + 256 + 4 * lane] = acc[bb][1];
        }
        __syncthreads();           // writes committed before reads
        if ((g >> 2) == r) {
#pragma unroll
            for (int q = 0; q < 16; ++q) {
                const float4 v =
                    *(const float4*)&uni[wv * 2048 + (g & 3) * 512 + 32 * q + 4 * p];
                hb[4 * q + 0] = v.x;
                hb[4 * q + 1] = v.y;
                hb[4 * q + 2] = v.z;
                hb[4 * q + 3] = v.w;
            }
        }
    }

    // ---- phase 2: OMP, 8 concurrent b (one per 8-lane group) ----
    float key[64];
#pragma unroll
    for (int e = 0; e < 64; ++e) key[e] = fabsf(hb[e]);

    unsigned msk0 = 0u, msk1 = 0u;
    int   I[KS];
    float xs[KS];
    float gsel[KS];
    float Lm[15];                   // packed lower-tri
    float invD[KS];                 // 1 / diag(L)

#pragma unroll
    for (int k = 0; k < KS; ++k) {
        // --- local argmax: running linear scan (3 live regs; do not widen) ---
        float bv = key[0]; int be = 0; float bhb = hb[0];
#pragma unroll
        for (int e = 1; e < 64; ++e) {
            bool gt = key[e] > bv;          // strict > keeps lowest e (n asc.)
            bv  = gt ? key[e] : bv;
            be  = gt ? e      : be;
            bhb = gt ? hb[e]  : bhb;
        }
        int bn = 32 * (be >> 2) + 4 * p + (be & 3);

        // --- 3-step reduce across the 8-lane group ---
#pragma unroll
        for (int off = 1; off < 8; off <<= 1) {
            float ov  = __shfl_xor(bv, off);
            int   on  = __shfl_xor(bn, off);
            float ohb = __shfl_xor(bhb, off);
            bool take = (ov > bv) || (ov == bv && on < bn);
            bv = take ? ov : bv; bn = take ? on : bn; bhb = take ? ohb : bhb;
        }
        const int nsel = bn;                // group-uniform
        I[k]    = nsel;
        gsel[k] = bhb;                      // = h_bar[nsel] (original), exact

        // mask the selected atom for future scans
        {
            int own  = (nsel >> 2) & 7;
            int esel = ((nsel >> 5) << 2) | (nsel & 3);
            if (p == own) {
                if (esel < 32) msk0 |= 1u << esel;
                else           msk1 |= 1u << (esel - 32);
            }
        }

        // --- Cholesky update of L ---
        if (k > 0) {
            float gk[KS - 1], w[KS - 1];
#pragma unroll
            for (int ti = 0; ti < KS - 1; ++ti)
                if (ti < k) gk[ti] = G[I[ti] * NATOM + nsel];
#pragma unroll
            for (int r = 0; r < KS - 1; ++r) {
                if (r < k) {
                    float s = gk[r];
#pragma unroll
                    for (int cc = 0; cc < KS - 1; ++cc)
                        if (cc < r) s -= Lm[r * (r + 1) / 2 + cc] * w[cc];
                    w[r] = s * invD[r];
                }
            }
            float s2 = 0.f;
#pragma unroll
            for (int r = 0; r < KS - 1; ++r) if (r < k) s2 += w[r] * w[r];
            float wc = sqrtf(fmaxf(0.f, 1.f - s2));
#pragma unroll
            for (int cc = 0; cc < KS - 1; ++cc)
                if (cc < k) Lm[k * (k + 1) / 2 + cc] = w[cc];
            Lm[k * (k + 1) / 2 + k] = wc;
            invD[k] = 1.0f / wc;            // one precise divide per k
        } else {
            Lm[0] = 1.f;
            invD[0] = 1.f;
        }

        // --- solve L y = gsel ; L^T x = y (replicated within group) ---
        float y[KS];
#pragma unroll
        for (int r = 0; r <= k; ++r) {
            float s = gsel[r];
#pragma unroll
            for (int cc = 0; cc < r; ++cc) s -= Lm[r * (r + 1) / 2 + cc] * y[cc];
            y[r] = s * invD[r];
        }
#pragma unroll
        for (int r = k; r >= 0; --r) {
            float s = y[r];
#pragma unroll
            for (int cc = r + 1; cc <= k; ++cc) s -= Lm[cc * (cc + 1) / 2 + r] * xs[cc];
            xs[r] = s * invD[r];
        }

        // --- fused beta + key update (no beta[] array; ascending-ti fma) ---
        if (k < KS - 1) {
#pragma unroll
            for (int q = 0; q < 16; ++q) {
                float bx = 0.f, by = 0.f, bz = 0.f, bw = 0.f;
#pragma unroll
                for (int ti = 0; ti < KS - 1; ++ti) {
                    if (ti <= k) {
                        const float4 gc = G4[I[ti] * 128 + 8 * q + p];
                        bx = fmaf(xs[ti], gc.x, bx);
                        by = fmaf(xs[ti], gc.y, by);
                        bz = fmaf(xs[ti], gc.z, bz);
                        bw = fmaf(xs[ti], gc.w, bw);
                    }
                }
                {
                    float d0 = hb[4 * q + 0] - bx;
                    float d1 = hb[4 * q + 1] - by;
                    float d2 = hb[4 * q + 2] - bz;
                    float d3 = hb[4 * q + 3] - bw;
                    const int e0 = 4 * q;
                    bool m0 = (e0 + 0 < 32) ? ((msk0 >> (e0 + 0)) & 1u) : ((msk1 >> (e0 - 32)) & 1u);
                    bool m1 = (e0 + 1 < 32) ? ((msk0 >> (e0 + 1)) & 1u) : ((msk1 >> (e0 + 1 - 32)) & 1u);
                    bool m2 = (e0 + 2 < 32) ? ((msk0 >> (e0 + 2)) & 1u) : ((msk1 >> (e0 + 2 - 32)) & 1u);
                    bool m3 = (e0 + 3 < 32) ? ((msk0 >> (e0 + 3)) & 1u) : ((msk1 >> (e0 + 3 - 32)) & 1u);
                    key[e0 + 0] = m0 ? -1.f : fabsf(d0);
                    key[e0 + 1] = m1 ? -1.f : fabsf(d1);
                    key[e0 + 2] = m2 ? -1.f : fabsf(d2);
                    key[e0 + 3] = m3 ? -1.f : fabsf(d3);
                }
            }
        }
    }

    if (p == 0) {
#pragma unroll
        for (int k = 0; k < KS; ++k) {
            idx_s[k][wv * 8 + g] = I[k];
            val_s[k][wv * 8 + g] = xs[k];
        }
    }
    __syncthreads();
    if (t < KS * 32) {
        int k = t >> 5, bb = t & 31;
        idx_out[k * B_TOTAL + b0 + bb] = idx_s[k][bb];
        val_out[k * B_TOTAL + b0 + bb] = val_s[k][bb];
    }
#undef DATA_S
}

// ---------------------------------------------------------------------------
// K3a: expand sparse (idx,val) into dense 512 x 32768 coefficients.
// 512 blocks (2/CU): 32 b-tiles x 16 j-chunks of 32. int4/float4 loads,
// float4 stores. (Separate kernel: fused tail measured +25us in R8.)
// ---------------------------------------------------------------------------
__global__ void k_coeff(const int* __restrict__ idx, const float* __restrict__ val,
                        float* __restrict__ coeff) {
    const int tile = blockIdx.x >> 4;            // 32 tiles of 1024 b
    const int jc   = blockIdx.x & 15;            // 16 j-chunks of 32
    const int b4   = tile * 1024 + threadIdx.x * 4;
    int4   I[KS]; float4 V[KS];
#pragma unroll
    for (int k = 0; k < KS; ++k) {
        I[k] = *(const int4*)  &idx[k * B_TOTAL + b4];
        V[k] = *(const float4*)&val[k * B_TOTAL + b4];
    }
    const int j0 = jc * 32;
#pragma unroll 4
    for (int j = j0; j < j0 + 32; ++j) {
        float4 w = make_float4(0.f, 0.f, 0.f, 0.f);
#pragma unroll
        for (int k = 0; k < KS; ++k) {
            w.x = (I[k].x == j) ? V[k].x : w.x;
            w.y = (I[k].y == j) ? V[k].y : w.y;
            w.z = (I[k].z == j) ? V[k].z : w.z;
            w.w = (I[k].w == j) ? V[k].w : w.w;
        }
        *(float4*)&coeff[j * B_TOTAL + b4] = w;
    }
}

// ---------------------------------------------------------------------------
// K3b: z_out + loss. b-major compute (coalesced idx/val/dataT reads,
// D row L1-hot), LDS tile transpose for coalesced z_e-layout writes.
// ---------------------------------------------------------------------------
__global__ void k_recon(const float* __restrict__ dataT, const float* __restrict__ D,
                        const int* __restrict__ idx, const float* __restrict__ val,
                        float* __restrict__ zout, float* __restrict__ acc) {
    const int n   = blockIdx.x >> 4;
    const int hw0 = (blockIdx.x & 15) * 64;
    const int t   = threadIdx.x;
    __shared__ float lds[64][65];
    float sq = 0.f;
#pragma unroll
    for (int r = 0; r < 16; ++r) {
        int id = r * 256 + t;
        int c = id & 63, j = id >> 6;
        int f = n * 65536 + (hw0 + j) * 64 + c;
        int b = f & 32767;
        int m = f >> 15;
        float zdl = 0.f;
#pragma unroll
        for (int k = 0; k < KS; ++k) {
            int   a = idx[k * B_TOTAL + b];
            float v = val[k * B_TOTAL + b];
            zdl = fmaf(v, D[m * NATOM + a], zdl);
        }
        float zp   = dataT[f];
        float diff = zdl - zp;
        lds[c][j] = zp + diff;
        sq = fmaf(diff, diff, sq);
    }
    __syncthreads();
#pragma unroll
    for (int r = 0; r < 16; ++r) {
        int id = r * 256 + t;
        int cc = id >> 6, i = id & 63;
        zout[n * 65536 + cc * 1024 + hw0 + i] = lds[cc][i];
    }
#pragma unroll
    for (int off = 32; off > 0; off >>= 1) sq += __shfl_xor(sq, off);
    __shared__ float red[4];
    if ((t & 63) == 0) red[t >> 6] = sq;
    __syncthreads();
    if (t == 0) atomicAdd(acc, red[0] + red[1] + red[2] + red[3]);
}

// ---------------------------------------------------------------------------
// K4: finalize loss = 1.25 * mean(diff^2)
// ---------------------------------------------------------------------------
__global__ void k_loss(const float* __restrict__ acc, float* __restrict__ out_loss) {
    if (threadIdx.x == 0 && blockIdx.x == 0)
        *out_loss = 1.25f * (*acc / 2097152.f);
}

// ---------------------------------------------------------------------------
extern "C" void kernel_launch(void* const* d_in, const int* in_sizes, int n_in,
                              void* d_out, int out_size, void* d_ws, size_t ws_size,
                              hipStream_t stream) {
    const float* ze = (const float*)d_in[0];
    const float* D  = (const float*)d_in[1];

    float* G     = (float*)d_ws;
    int*   idxp  = (int*)  ((char*)d_ws + (size_t)262144 * 4);
    float* valp  = (float*)((char*)d_ws + (size_t)(262144 + 163840) * 4);
    float* accp  = (float*)((char*)d_ws + (size_t)(262144 + 2 * 163840) * 4);
    float* dataT = (float*)((char*)d_ws + (size_t)(262144 + 2 * 163840 + 64) * 4);

    float* zout  = (float*)d_out;
    float* lossp = zout + 2097152;
    float* coeff = zout + 2097153;

    k_prep <<<1024, 256, 0, stream>>>(ze, dataT, D, G, accp);
    k_omp  <<<1024, 256, 0, stream>>>(dataT, D, G, idxp, valp);
    k_coeff<<<512, 256, 0, stream>>>(idxp, valp, coeff);
    k_recon<<<512, 256, 0, stream>>>(dataT, D, idxp, valp, zout, accp);
    k_loss <<<1, 64, 0, stream>>>(accp, lossp);
}